// Round 1
// baseline (104.625 us; speedup 1.0000x reference)
//
#include <hip/hip_runtime.h>
#include <math.h>

// Blobber: out = sig2(box3(sig1(box3(in)))), one iteration (reference's 4
// iterations all restart from `inputs`, so they collapse to one).
// in/out: 32 x 1 x 512 x 512 fp32. Memory-bound: ideal ~64 MB HBM traffic.

#define IMG_H 512
#define IMG_W 512
#define NB    32

#define TX 64            // output tile width  (x contiguous)
#define TY 16            // output tile height
#define RX (TX + 4)      // input region width  (halo 2 each side) = 68
#define RY (TY + 4)      // input region height = 20
#define SX (TX + 2)      // s1 region width  (halo 1) = 66
#define SY (TY + 2)      // s1 region height = 18

__device__ __forceinline__ float steep_sigmoid(double t, double c) {
    // sigmoid((t - c) * 1000), t accumulated in double so the x1000
    // amplification doesn't blow up conv rounding error.
    float x = (float)((t - c) * 1000.0);
    // saturates cleanly: expf(+inf-ish)=inf -> 0, expf(-big)=0 -> 1
    return 1.0f / (1.0f + expf(-x));
}

__global__ __launch_bounds__(256) void blobber_fused(
        const float* __restrict__ in, float* __restrict__ out) {
    __shared__ float sIn[RY][RX];   // 68*20*4 = 5440 B
    __shared__ float sS1[SY][SX];   // 66*18*4 = 4752 B

    const int tid = threadIdx.x;
    const int x0  = blockIdx.x * TX;     // 8 tiles across
    const int y0  = blockIdx.y * TY;     // 32 tiles down
    const int b   = blockIdx.z;          // batch

    const float* img  = in  + (size_t)b * IMG_H * IMG_W;
    float*       oimg = out + (size_t)b * IMG_H * IMG_W;

    // ---- stage 0: load input tile + halo(2), zero-padded at image edges ----
    for (int idx = tid; idx < RX * RY; idx += 256) {
        int iy = idx / RX;
        int ix = idx - iy * RX;
        int gx = x0 - 2 + ix;
        int gy = y0 - 2 + iy;
        float v = 0.0f;
        if ((unsigned)gx < (unsigned)IMG_W && (unsigned)gy < (unsigned)IMG_H)
            v = img[gy * IMG_W + gx];
        sIn[iy][ix] = v;
    }
    __syncthreads();

    // ---- stage 1: s1 = sig1(box3(in)) on the 66x18 halo(1) region ----
    // s1 cell (sx,sy) is global pixel (x0-1+sx, y0-1+sy); its 3x3 taps are
    // sIn[sy+dy][sx+dx], dy,dx in 0..2 (region origin is (x0-2, y0-2)).
    // IMPORTANT: positions outside the image must be literal 0 (conv2 pads
    // s1 with zeros) — NOT sigmoid(-10) = 4.5e-5.
    for (int idx = tid; idx < SX * SY; idx += 256) {
        int sy = idx / SX;
        int sx = idx - sy * SX;
        int gx = x0 - 1 + sx;
        int gy = y0 - 1 + sy;
        float v = 0.0f;
        if ((unsigned)gx < (unsigned)IMG_W && (unsigned)gy < (unsigned)IMG_H) {
            double t = 0.0;
            #pragma unroll
            for (int dy = 0; dy < 3; ++dy)
                #pragma unroll
                for (int dx = 0; dx < 3; ++dx)
                    t += (double)sIn[sy + dy][sx + dx];
            t *= (1.0 / 9.0);
            v = steep_sigmoid(t, 0.01);
        }
        sS1[sy][sx] = v;
    }
    __syncthreads();

    // ---- stage 2: out = sig2(box3(s1)) on the 64x16 tile ----
    for (int idx = tid; idx < TX * TY; idx += 256) {
        int oy = idx >> 6;          // TX = 64
        int ox = idx & 63;
        double t = 0.0;
        #pragma unroll
        for (int dy = 0; dy < 3; ++dy)
            #pragma unroll
            for (int dx = 0; dx < 3; ++dx)
                t += (double)sS1[oy + dy][ox + dx];
        t *= (1.0 / 9.0);
        oimg[(y0 + oy) * IMG_W + (x0 + ox)] = steep_sigmoid(t, 0.9);
    }
}

extern "C" void kernel_launch(void* const* d_in, const int* in_sizes, int n_in,
                              void* d_out, int out_size, void* d_ws, size_t ws_size,
                              hipStream_t stream) {
    const float* in  = (const float*)d_in[0];
    float*       out = (float*)d_out;
    dim3 grid(IMG_W / TX, IMG_H / TY, NB);   // 8 x 32 x 32 = 8192 blocks
    blobber_fused<<<grid, 256, 0, stream>>>(in, out);
}

// Round 2
// 98.824 us; speedup vs baseline: 1.0587x; 1.0587x over previous
//
#include <hip/hip_runtime.h>

// Blobber: out = sig2(box3(sig1(box3(in)))) — the reference's 4 iterations all
// restart from `inputs`, so they collapse to one iteration.
// in/out: 32 x 1 x 512 x 512 fp32. HBM floor ~64 MB -> ~10 us.
//
// All fp32: the x1000 steep sigmoids saturate (s1 is exactly 1.0f almost
// everywhere); fp32 sum error (~2.4e-6) maps to <=7e-5 output error and only
// at threshold-straddling pixels (prob ~1e-10/pixel). Threshold is 2e-2.

#define IMG 512
#define NB  32

#define TX 64            // output tile width (x, contiguous)
#define TY 32            // output tile height
#define RX 68            // input region width  (halo 2)
#define RY 36            // input region height
#define RXP 72           // padded LDS stride
#define SX 66            // s1 region width (halo 1)
#define SY 34            // s1 region height
#define SXP 68

// sigmoid((sum9/9 - c)*1000) = sigmoid(fma(sum9, 1000/9, -1000c))
__device__ __forceinline__ float steep_sig(float sum9, float bias) {
    float x = fmaf(sum9, 1000.0f / 9.0f, bias);
    float e = __expf(-x);                      // native v_exp_f32 path
    return __builtin_amdgcn_rcpf(1.0f + e);    // raw v_rcp_f32, ~1 ulp
}

__global__ __launch_bounds__(256, 4) void blobber_fused(
        const float* __restrict__ in, float* __restrict__ out) {
    __shared__ float sIn[RY][RXP];   // 36*72*4 = 10368 B
    __shared__ float sS1[SY][SXP];   // 34*68*4 =  9248 B

    const int tid = threadIdx.x;
    const int tx  = tid & 63;        // column within tile
    const int tyg = tid >> 6;        // row group 0..3
    const int x0  = blockIdx.x * TX;
    const int y0  = blockIdx.y * TY;

    const float* img  = in  + (size_t)blockIdx.z * (IMG * IMG);
    float*       oimg = out + (size_t)blockIdx.z * (IMG * IMG);

    // ---- Phase A: load RY x RX input region (origin x0-2, y0-2), 0-padded ----
    #pragma unroll
    for (int iy = tyg; iy < RY; iy += 4) {
        int gy = y0 - 2 + iy;
        bool rowok = (unsigned)gy < IMG;
        const float* row = img + gy * IMG;
        int gx = x0 - 2 + tx;
        sIn[iy][tx] = (rowok && (unsigned)gx < IMG) ? row[gx] : 0.0f;
        if (tx < 4) {                          // columns 64..67
            int gx2 = gx + 64;
            sIn[iy][tx + 64] = (rowok && (unsigned)gx2 < IMG) ? row[gx2] : 0.0f;
        }
    }
    __syncthreads();

    // ---- Phase B: s1 = sig1(box3(in)) on SY x SX region (origin x0-1,y0-1) --
    // OOB s1 cells must be literal 0 (conv2 zero-pads s1), not sig1(0-conv).
    #pragma unroll
    for (int iy = tyg; iy < SY; iy += 4) {
        int gy = y0 - 1 + iy;
        bool rowok = (unsigned)gy < IMG;
        {
            int sx = tx;
            int gx = x0 - 1 + sx;
            float t = 0.0f;
            #pragma unroll
            for (int dy = 0; dy < 3; ++dy)
                t += sIn[iy + dy][sx] + sIn[iy + dy][sx + 1] + sIn[iy + dy][sx + 2];
            sS1[iy][sx] = (rowok && (unsigned)gx < IMG) ? steep_sig(t, -10.0f) : 0.0f;
        }
        if (tx < 2) {                          // columns 64..65
            int sx = 64 + tx;
            int gx = x0 - 1 + sx;
            float t = 0.0f;
            #pragma unroll
            for (int dy = 0; dy < 3; ++dy)
                t += sIn[iy + dy][sx] + sIn[iy + dy][sx + 1] + sIn[iy + dy][sx + 2];
            sS1[iy][sx] = (rowok && (unsigned)gx < IMG) ? steep_sig(t, -10.0f) : 0.0f;
        }
    }
    __syncthreads();

    // ---- Phase C: out = sig2(box3(s1)) on TY x TX tile ----
    #pragma unroll
    for (int oy = tyg; oy < TY; oy += 4) {
        float t = 0.0f;
        #pragma unroll
        for (int dy = 0; dy < 3; ++dy)
            t += sS1[oy + dy][tx] + sS1[oy + dy][tx + 1] + sS1[oy + dy][tx + 2];
        oimg[(y0 + oy) * IMG + x0 + tx] = steep_sig(t, -900.0f);
    }
}

extern "C" void kernel_launch(void* const* d_in, const int* in_sizes, int n_in,
                              void* d_out, int out_size, void* d_ws, size_t ws_size,
                              hipStream_t stream) {
    const float* in  = (const float*)d_in[0];
    float*       out = (float*)d_out;
    dim3 grid(IMG / TX, IMG / TY, NB);   // 8 x 16 x 32 = 4096 blocks
    blobber_fused<<<grid, 256, 0, stream>>>(in, out);
}

// Round 3
// 90.333 us; speedup vs baseline: 1.1582x; 1.0940x over previous
//
#include <hip/hip_runtime.h>

// Blobber: out = sig2(box3(sig1(box3(in)))) — the reference's 4 iterations all
// restart from `inputs`, so they collapse to one iteration.
// in/out: 32 x 1 x 512 x 512 fp32. HBM floor ~64 MB -> ~10.5 us.
//
// R2 post-mortem: 18 scalar ds_read_b32 per pixel made the kernel LDS-issue
// bound (~23 us of LDS pipe). This version separates the box filter
// (vertical 3-sum then horizontal 3-sum) and moves ALL LDS traffic to
// aligned float4 (ds_read_b128 / ds_write_b128), cutting LDS wave-instrs ~6x.
//
// Phases (per 64x32 output tile):
//   A: global -> sIn  (36 rows x 18 quads, cols x0-4..x0+67, zero-padded)
//   B: sV1 = vertical 3-sum of sIn (34 rows x 18 data quads + zero guard quads)
//   C: sS1 = sig1(horizontal 3-sum of sV1), zeroed outside image (conv2
//      zero-pads s1 itself, NOT sig1(0) = 4.5e-5)
//   D: sH2 = horizontal 3-sum of sS1 (out columns only)
//   E: out = sig2(vertical 3-sum of sH2)
// All tile/image boundaries are 4-aligned -> every OOB mask is quad-uniform.

#define IMG 512
#define NB  32
#define TX  64
#define TY  32

__device__ __forceinline__ float4 f4add3(float4 a, float4 b, float4 c) {
    float4 r;
    r.x = a.x + b.x + c.x;
    r.y = a.y + b.y + c.y;
    r.z = a.z + b.z + c.z;
    r.w = a.w + b.w + c.w;
    return r;
}

// sigmoid((sum9/9 - c)*1000) = sigmoid(fma(sum9, 1000/9, -1000c))
// Saturation: __expf(+-990) -> 0 / inf; rcp(inf)=0, rcp(1)=1. Clean.
__device__ __forceinline__ float steep_sig(float sum9, float bias) {
    float x = fmaf(sum9, 1000.0f / 9.0f, bias);
    float e = __expf(-x);
    return __builtin_amdgcn_rcpf(1.0f + e);
}

__global__ __launch_bounds__(256, 4) void blobber_fused(
        const float* __restrict__ in, float* __restrict__ out) {
    // quad q of sIn/sS1 covers image cols x0-4+4q ; sV1 quad k covers x0-8+4k
    __shared__ float4 sIn[TY + 4][18];   // 36*18*16 = 10368 B
    __shared__ float4 sV1[TY + 2][20];   // 34*20*16 = 10880 B (k=0,19 zero guards)
    __shared__ float4 sS1[TY + 2][18];   // 34*18*16 =  9792 B
    __shared__ float4 sH2[TY + 2][16];   // 34*16*16 =  8704 B   total 39744 B

    const int tid = threadIdx.x;
    const int x0  = blockIdx.x * TX;
    const int y0  = blockIdx.y * TY;
    const float* img  = in  + (size_t)blockIdx.z * (IMG * IMG);
    float*       oimg = out + (size_t)blockIdx.z * (IMG * IMG);

    // ---- Phase A: load input region + zero V1 guard quads ----
    for (int it = tid; it < (TY + 4) * 18; it += 256) {
        int r = it / 18;
        int q = it - r * 18;
        int gy = y0 - 2 + r;
        int gx = x0 - 4 + 4 * q;           // quad-uniform; 4-aligned vs 0/512
        float4 v = make_float4(0.f, 0.f, 0.f, 0.f);
        if ((unsigned)gy < IMG && (unsigned)gx < IMG)
            v = *(const float4*)(img + gy * IMG + gx);
        sIn[r][q] = v;
    }
    for (int it = tid; it < (TY + 2) * 2; it += 256) {
        int r = it >> 1;
        sV1[r][(it & 1) * 19] = make_float4(0.f, 0.f, 0.f, 0.f);
    }
    __syncthreads();

    // ---- Phase B: vertical 3-sum of input ----
    for (int it = tid; it < (TY + 2) * 18; it += 256) {
        int r = it / 18;
        int q = it - r * 18;
        sV1[r][q + 1] = f4add3(sIn[r][q], sIn[r + 1][q], sIn[r + 2][q]);
    }
    __syncthreads();

    // ---- Phase C: s1 = sig1(horizontal 3-sum of V1), zero outside image ----
    for (int it = tid; it < (TY + 2) * 18; it += 256) {
        int r = it / 18;
        int j = it - r * 18;
        int gy = y0 - 1 + r;
        int gx = x0 - 4 + 4 * j;           // quad-uniform mask
        float4 s = make_float4(0.f, 0.f, 0.f, 0.f);
        if ((unsigned)gy < IMG && (unsigned)gx < IMG) {
            float4 A = sV1[r][j], B = sV1[r][j + 1], C = sV1[r][j + 2];
            s.x = steep_sig(A.w + B.x + B.y, -10.0f);
            s.y = steep_sig(B.x + B.y + B.z, -10.0f);
            s.z = steep_sig(B.y + B.z + B.w, -10.0f);
            s.w = steep_sig(B.z + B.w + C.x, -10.0f);
        }
        sS1[r][j] = s;
    }
    __syncthreads();

    // ---- Phase D: horizontal 3-sum of s1 (out columns only) ----
    for (int it = tid; it < (TY + 2) * 16; it += 256) {
        int r = it >> 4;
        int m = it & 15;
        float4 A = sS1[r][m], B = sS1[r][m + 1], C = sS1[r][m + 2];
        float4 h;
        h.x = A.w + B.x + B.y;
        h.y = B.x + B.y + B.z;
        h.z = B.y + B.z + B.w;
        h.w = B.z + B.w + C.x;
        sH2[r][m] = h;
    }
    __syncthreads();

    // ---- Phase E: out = sig2(vertical 3-sum of H2) ----
    for (int it = tid; it < TY * 16; it += 256) {
        int r = it >> 4;
        int m = it & 15;
        float4 a = sH2[r][m], b = sH2[r + 1][m], c = sH2[r + 2][m];
        float4 o;
        o.x = steep_sig(a.x + b.x + c.x, -900.0f);
        o.y = steep_sig(a.y + b.y + c.y, -900.0f);
        o.z = steep_sig(a.z + b.z + c.z, -900.0f);
        o.w = steep_sig(a.w + b.w + c.w, -900.0f);
        *(float4*)(oimg + (y0 + r) * IMG + x0 + 4 * m) = o;
    }
}

extern "C" void kernel_launch(void* const* d_in, const int* in_sizes, int n_in,
                              void* d_out, int out_size, void* d_ws, size_t ws_size,
                              hipStream_t stream) {
    const float* in  = (const float*)d_in[0];
    float*       out = (float*)d_out;
    dim3 grid(IMG / TX, IMG / TY, NB);   // 8 x 16 x 32 = 4096 blocks
    blobber_fused<<<grid, 256, 0, stream>>>(in, out);
}

// Round 5
// 83.905 us; speedup vs baseline: 1.2469x; 1.0766x over previous
//
#include <hip/hip_runtime.h>

// Blobber: out = sig2(box3(sig1(box3(in)))) — the reference's 4 iterations all
// restart from `inputs`, so they collapse to one iteration.
// in/out: 32 x 1 x 512 x 512 fp32.
//
// R4 post-mortem: the 256-px strip kernel (edge-lane halo loads + s1h strip
// sigmoid) failed correctness; the halo machinery was the suspicion-dense
// part. This version: each wave owns a FULL 512-px-wide band of 8 rows, so
// the only horizontal boundaries are the image edges (zero) and the L/R seam
// at col 255/256 (two broadcast shuffles). All 12 input rows are loaded up
// front into registers (24 independent dwordx4 -> deep MLP), then the whole
// s1 -> h2 -> out pipeline runs in registers. No LDS, no __syncthreads.
//
// Per s1 row r: v3 = in(r-1)+in(r)+in(r+1) (rows zero-padded);
// s1 = sig1(h3(v3)), forced 0 for OOB rows (conv2 zero-pads s1 itself,
// NOT sig1(0)=4.5e-5); h2 = h3(s1); out(y) = sig2(h2(y-1)+h2(y)+h2(y+1)).

#define IMG 512
#define BH  8             // output rows per wave
#define NROWS (BH + 4)    // 12 input rows resident in registers
#define NIT   (BH + 2)    // 10 s1/h2 rows

// sigmoid((sum9/9 - c)*1000) = sigmoid(fma(sum9, 1000/9, -1000c))
__device__ __forceinline__ float steep_sig(float sum9, float bias) {
    float x = fmaf(sum9, 1000.0f / 9.0f, bias);
    return __builtin_amdgcn_rcpf(1.0f + __expf(-x));
}

__device__ __forceinline__ float4 f4add3(float4 a, float4 b, float4 c) {
    return make_float4(a.x + b.x + c.x, a.y + b.y + c.y,
                       a.z + b.z + c.z, a.w + b.w + c.w);
}

__global__ __launch_bounds__(256) void blobber_fused(const float* __restrict__ in,
                                                     float* __restrict__ out) {
    const int tid  = threadIdx.x;
    const int lane = tid & 63;
    const int gw   = blockIdx.x * 4 + (tid >> 6);   // 2048 waves
    const int band = gw & 63;                       // 64 bands x 8 rows
    const int img  = gw >> 6;                       // 32 images
    const int y0   = band * BH;

    const int colL = 4 * lane;         // L half: cols 0..255, coalesced
    const int colR = 256 + 4 * lane;   // R half: cols 256..511, coalesced

    const float* ip = in  + (size_t)img * (IMG * IMG);
    float*       op = out + (size_t)img * (IMG * IMG);

    // ---- load all 12 input rows (y0-2 .. y0+9), zero for OOB rows ----
    float4 inL[NROWS], inR[NROWS];
    #pragma unroll
    for (int k = 0; k < NROWS; ++k) {
        const int r = y0 - 2 + k;
        inL[k] = make_float4(0.f, 0.f, 0.f, 0.f);
        inR[k] = make_float4(0.f, 0.f, 0.f, 0.f);
        if ((unsigned)r < IMG) {                    // wave-uniform
            inL[k] = *(const float4*)(ip + r * IMG + colL);
            inR[k] = *(const float4*)(ip + r * IMG + colR);
        }
    }

    const float4 z4 = make_float4(0.f, 0.f, 0.f, 0.f);
    float4 h2mL = z4, h2cL = z4, h2mR = z4, h2cR = z4;

    #pragma unroll
    for (int s = 0; s < NIT; ++s) {
        const int r = y0 - 1 + s;                   // s1/h2 row being produced

        // vertical 3-sum (input rows r-1..r+1 = k s..s+2)
        float4 vL = f4add3(inL[s], inL[s + 1], inL[s + 2]);
        float4 vR = f4add3(inR[s], inR[s + 1], inR[s + 2]);

        // horizontal neighbors of v3 (full-exec shuffles, per-lane fixups)
        float Llft = __shfl_up(vL.w, 1);
        float Lrgt = __shfl_down(vL.x, 1);
        float Rlft = __shfl_up(vR.w, 1);
        float Rrgt = __shfl_down(vR.x, 1);
        float c256 = __shfl(vR.x, 0);               // v3 at col 256
        float c255 = __shfl(vL.w, 63);              // v3 at col 255
        if (lane == 0)  { Llft = 0.0f;  Rlft = c255; }   // col -1 -> 0
        if (lane == 63) { Lrgt = c256;  Rrgt = 0.0f; }   // col 512 -> 0

        // stage 1: s1 = sig1(h3(v3)); OOB rows are literal 0
        float4 s1L, s1R;
        if ((unsigned)r < IMG) {                    // wave-uniform
            s1L.x = steep_sig(Llft + vL.x + vL.y, -10.0f);
            s1L.y = steep_sig(vL.x + vL.y + vL.z, -10.0f);
            s1L.z = steep_sig(vL.y + vL.z + vL.w, -10.0f);
            s1L.w = steep_sig(vL.z + vL.w + Lrgt, -10.0f);
            s1R.x = steep_sig(Rlft + vR.x + vR.y, -10.0f);
            s1R.y = steep_sig(vR.x + vR.y + vR.z, -10.0f);
            s1R.z = steep_sig(vR.y + vR.z + vR.w, -10.0f);
            s1R.w = steep_sig(vR.z + vR.w + Rrgt, -10.0f);
        } else {
            s1L = z4; s1R = z4;
        }

        // stage 2 horizontal: h2 = h3(s1)
        float sLl = __shfl_up(s1L.w, 1);
        float sLr = __shfl_down(s1L.x, 1);
        float sRl = __shfl_up(s1R.w, 1);
        float sRr = __shfl_down(s1R.x, 1);
        float s256 = __shfl(s1R.x, 0);              // s1 at col 256
        float s255 = __shfl(s1L.w, 63);             // s1 at col 255
        if (lane == 0)  { sLl = 0.0f;  sRl = s255; }
        if (lane == 63) { sLr = s256;  sRr = 0.0f; }

        float4 h2pL, h2pR;
        h2pL.x = sLl   + s1L.x + s1L.y;
        h2pL.y = s1L.x + s1L.y + s1L.z;
        h2pL.z = s1L.y + s1L.z + s1L.w;
        h2pL.w = s1L.z + s1L.w + sLr;
        h2pR.x = sRl   + s1R.x + s1R.y;
        h2pR.y = s1R.x + s1R.y + s1R.z;
        h2pR.z = s1R.y + s1R.z + s1R.w;
        h2pR.w = s1R.z + s1R.w + sRr;

        // output row r-1 = sig2(vertical 3-sum of h2 rows r-2..r)
        if (s >= 2) {
            const int oy = r - 1;                   // y0 .. y0+7
            float4 oL, oR;
            oL.x = steep_sig(h2mL.x + h2cL.x + h2pL.x, -900.0f);
            oL.y = steep_sig(h2mL.y + h2cL.y + h2pL.y, -900.0f);
            oL.z = steep_sig(h2mL.z + h2cL.z + h2pL.z, -900.0f);
            oL.w = steep_sig(h2mL.w + h2cL.w + h2pL.w, -900.0f);
            oR.x = steep_sig(h2mR.x + h2cR.x + h2pR.x, -900.0f);
            oR.y = steep_sig(h2mR.y + h2cR.y + h2pR.y, -900.0f);
            oR.z = steep_sig(h2mR.z + h2cR.z + h2pR.z, -900.0f);
            oR.w = steep_sig(h2mR.w + h2cR.w + h2pR.w, -900.0f);
            *(float4*)(op + oy * IMG + colL) = oL;
            *(float4*)(op + oy * IMG + colR) = oR;
        }

        h2mL = h2cL; h2cL = h2pL;
        h2mR = h2cR; h2cR = h2pR;
    }
}

extern "C" void kernel_launch(void* const* d_in, const int* in_sizes, int n_in,
                              void* d_out, int out_size, void* d_ws, size_t ws_size,
                              hipStream_t stream) {
    const float* in  = (const float*)d_in[0];
    float*       out = (float*)d_out;
    // 2048 waves = 512 blocks x 4 waves (32 imgs x 64 bands)
    blobber_fused<<<dim3(512), dim3(256), 0, stream>>>(in, out);
}